// Round 4
// baseline (6796.725 us; speedup 1.0000x reference)
//
#include <hip/hip_runtime.h>
#include <cstdint>
#include <cstddef>

// ---------------------------------------------------------------------------
// DeeperGCN forward on MI355X. Round 4: single persistent megakernel with
// hand-rolled grid barriers (768 blocks x 256 thr, 3 blocks/CU co-resident).
// Fix vs round 3: pool read the wrong half of the r double-buffer (one layer
// stale). Last layer i=L-1 writes r0 when L is even.
// N=10000 nodes, E=160000 edges, H=128, L=14 layers, G=64 graphs.
// ---------------------------------------------------------------------------

#define GD 768
#define BT 256

typedef __attribute__((ext_vector_type(8))) short bf16x8;
typedef __attribute__((ext_vector_type(4))) float f32x4;

__device__ inline float bf2f(ushort u) {
    union { uint i; float f; } v;
    v.i = (uint)u << 16;
    return v.f;
}
__device__ inline ushort f2bf(float f) {
    union { float f; uint i; } v;
    v.f = f;
    return (ushort)((v.i + 0x7fffu + ((v.i >> 16) & 1u)) >> 16);
}
__device__ inline uint f2bf2(float a, float b) {
    return (uint)f2bf(a) | ((uint)f2bf(b) << 16);
}

__device__ inline float wave_sum_f(float v) {
#pragma unroll
    for (int off = 32; off > 0; off >>= 1) v += __shfl_xor(v, off, 64);
    return v;
}
__device__ inline int wave_sum_i(int v) {
#pragma unroll
    for (int off = 32; off > 0; off >>= 1) v += __shfl_xor(v, off, 64);
    return v;
}

struct Args {
    const int* src; const int* dst; const int* batch;
    const float* x; const float* encW; const float* encB;
    const float* ln_g; const float* ln_b; const float* tArr; const float* scArr;
    const float* W1; const float* b1; const float* mg; const float* mb;
    const float* W2; const float* b2; const float* fn_g; const float* fn_b;
    float* out;
    int* bar; int* deg; int* offs; int* cursor; int* esrc;
    int* chunkSum; int* chunkOff; int* gstart;
    float* h; ushort* r0; ushort* r1; float* rn;
    ushort* xb; ushort* W1t; ushort* W2t; ushort* encWt;
    int N, E, L, G;
};

// monotonic grid barrier: every block calls it the same number of times.
__device__ inline void grid_sync(int* bar, int& gen) {
    __threadfence();
    __syncthreads();
    if (threadIdx.x == 0) {
        gen += 1;
        __hip_atomic_fetch_add(bar, 1, __ATOMIC_ACQ_REL, __HIP_MEMORY_SCOPE_AGENT);
        while (__hip_atomic_load(bar, __ATOMIC_ACQUIRE, __HIP_MEMORY_SCOPE_AGENT) < gen * GD)
            __builtin_amdgcn_s_sleep(2);
    }
    __syncthreads();
}

// ---- aggregation for 16-node tile; writes u rows (bf16 pairs) into AsU ----
__device__ __forceinline__ void agg_stage(const ushort* __restrict__ rin,
                                          const int* __restrict__ offs,
                                          const int* __restrict__ esrc,
                                          const float* __restrict__ rnbuf,
                                          float tv, float sv, int row0,
                                          int w, int l, uint (*AsU)[68]) {
#pragma unroll 1
    for (int k = 0; k < 4; k++) {
        int nd = row0 + w * 4 + k;
        int e0 = offs[nd], e1 = offs[nd + 1];
        float m0 = -INFINITY, m1 = -INFINITY;
        float s0 = 0.f, s1 = 0.f, w0 = 0.f, w1 = 0.f;
        for (int j = e0; j < e1; j++) {
            int sn = esrc[j];
            uint rv = ((const uint*)rin)[(size_t)sn * 64 + l];
            float x0 = bf2f((ushort)(rv & 0xffff));
            float x1 = bf2f((ushort)(rv >> 16));
            float g0 = fmaxf(x0, 0.f) + 1e-7f;
            float g1 = fmaxf(x1, 0.f) + 1e-7f;
            float z0 = g0 * tv, z1v = g1 * tv;
            float nm0 = fmaxf(m0, z0), nm1 = fmaxf(m1, z1v);
            float a0 = __expf(m0 - nm0), a1 = __expf(m1 - nm1);
            float p0 = __expf(z0 - nm0), p1 = __expf(z1v - nm1);
            s0 = s0 * a0 + p0;
            s1 = s1 * a1 + p1;
            w0 = w0 * a0 + g0 * p0;
            w1 = w1 * a1 + g1 * p1;
            m0 = nm0;
            m1 = nm1;
        }
        float agg0 = w0 / (s0 + 1e-16f);
        float agg1 = w1 / (s1 + 1e-16f);
        float nr = sqrtf(wave_sum_f(agg0 * agg0 + agg1 * agg1));
        float fac = rnbuf[nd] * sv / fmaxf(nr, 1e-12f);
        uint ru = ((const uint*)rin)[(size_t)nd * 64 + l];
        float r0v = bf2f((ushort)(ru & 0xffff));
        float r1v = bf2f((ushort)(ru >> 16));
        AsU[w * 4 + k][l] = f2bf2(r0v + agg0 * fac, r1v + agg1 * fac);
    }
}

// ---- gemm1: z1 = relu(LN256(A(16x128) @ W1^T + b1)) into z1s LDS ----
__device__ __forceinline__ void gemm1_stage(const ushort (*As)[136],
                                            const ushort* __restrict__ Bt,
                                            const float* __restrict__ bias,
                                            const float* __restrict__ mg,
                                            const float* __restrict__ mb,
                                            ushort (*z1s)[264],
                                            int w, int q, int ln,
                                            float (*pS)[16], float (*pQ)[16]) {
    f32x4 acc[4];
#pragma unroll
    for (int ct = 0; ct < 4; ct++) acc[ct] = (f32x4){0.f, 0.f, 0.f, 0.f};
#pragma unroll
    for (int ks = 0; ks < 128; ks += 32) {
        bf16x8 a = *(const bf16x8*)&As[ln][ks + q * 8];
#pragma unroll
        for (int ct = 0; ct < 4; ct++) {
            bf16x8 bv = *(const bf16x8*)(Bt + (size_t)(w * 64 + ct * 16 + ln) * 128 + ks + q * 8);
            acc[ct] = __builtin_amdgcn_mfma_f32_16x16x32_bf16(a, bv, acc[ct], 0, 0, 0);
        }
    }
    float s1[4] = {0, 0, 0, 0}, s2[4] = {0, 0, 0, 0};
#pragma unroll
    for (int ct = 0; ct < 4; ct++)
#pragma unroll
        for (int r = 0; r < 4; r++) {
            float v = acc[ct][r] + bias[w * 64 + ct * 16 + ln];
            acc[ct][r] = v;
            s1[r] += v;
            s2[r] += v * v;
        }
#pragma unroll
    for (int off = 1; off < 16; off <<= 1)
#pragma unroll
        for (int r = 0; r < 4; r++) {
            s1[r] += __shfl_xor(s1[r], off, 64);
            s2[r] += __shfl_xor(s2[r], off, 64);
        }
    if (ln == 0)
#pragma unroll
        for (int r = 0; r < 4; r++) {
            pS[w][q * 4 + r] = s1[r];
            pQ[w][q * 4 + r] = s2[r];
        }
    __syncthreads();
#pragma unroll
    for (int r = 0; r < 4; r++) {
        int row = q * 4 + r;
        float S = pS[0][row] + pS[1][row] + pS[2][row] + pS[3][row];
        float Q = pQ[0][row] + pQ[1][row] + pQ[2][row] + pQ[3][row];
        float mu = S * (1.f / 256.f);
        float var = Q * (1.f / 256.f) - mu * mu;
        float rs = rsqrtf(var + 1e-5f);
#pragma unroll
        for (int ct = 0; ct < 4; ct++) {
            int col = w * 64 + ct * 16 + ln;
            float y = (acc[ct][r] - mu) * rs * mg[col] + mb[col];
            z1s[row][col] = f2bf(fmaxf(y, 0.f));
        }
    }
    __syncthreads();
}

// ---- output gemm: v = A(16xKD) @ B^T + bias (+h); h=v; LN128 -> lrelu ->
// rout (bf16), rn = ||row||. ----
template <int KD, bool RESID>
__device__ __forceinline__ void out_stage(const ushort* __restrict__ Abase, int astr,
                                          const ushort* __restrict__ Bt,
                                          const float* __restrict__ bias,
                                          const float* __restrict__ lg,
                                          const float* __restrict__ lb,
                                          float* __restrict__ hbuf,
                                          ushort* __restrict__ rout,
                                          float* __restrict__ rnbuf,
                                          int row0, int w, int q, int ln,
                                          float (*pS)[16], float (*pQ)[16]) {
    f32x4 acc[2];
    acc[0] = (f32x4){0.f, 0.f, 0.f, 0.f};
    acc[1] = (f32x4){0.f, 0.f, 0.f, 0.f};
#pragma unroll
    for (int ks = 0; ks < KD; ks += 32) {
        bf16x8 a = *(const bf16x8*)(Abase + ln * astr + ks + q * 8);
#pragma unroll
        for (int ct = 0; ct < 2; ct++) {
            bf16x8 bv = *(const bf16x8*)(Bt + (size_t)(w * 32 + ct * 16 + ln) * KD + ks + q * 8);
            acc[ct] = __builtin_amdgcn_mfma_f32_16x16x32_bf16(a, bv, acc[ct], 0, 0, 0);
        }
    }
    float s1[4] = {0, 0, 0, 0}, s2[4] = {0, 0, 0, 0};
#pragma unroll
    for (int ct = 0; ct < 2; ct++)
#pragma unroll
        for (int r = 0; r < 4; r++) {
            int row = q * 4 + r, col = w * 32 + ct * 16 + ln;
            float v = acc[ct][r] + bias[col];
            if (RESID) v += hbuf[(size_t)(row0 + row) * 128 + col];
            hbuf[(size_t)(row0 + row) * 128 + col] = v;
            acc[ct][r] = v;
            s1[r] += v;
            s2[r] += v * v;
        }
#pragma unroll
    for (int off = 1; off < 16; off <<= 1)
#pragma unroll
        for (int r = 0; r < 4; r++) {
            s1[r] += __shfl_xor(s1[r], off, 64);
            s2[r] += __shfl_xor(s2[r], off, 64);
        }
    if (ln == 0)
#pragma unroll
        for (int r = 0; r < 4; r++) {
            pS[w][q * 4 + r] = s1[r];
            pQ[w][q * 4 + r] = s2[r];
        }
    __syncthreads();
    float yv[2][4];
    float t2[4] = {0, 0, 0, 0};
#pragma unroll
    for (int r = 0; r < 4; r++) {
        int row = q * 4 + r;
        float S = pS[0][row] + pS[1][row] + pS[2][row] + pS[3][row];
        float Q = pQ[0][row] + pQ[1][row] + pQ[2][row] + pQ[3][row];
        float mu = S * (1.f / 128.f);
        float var = Q * (1.f / 128.f) - mu * mu;
        float rs = rsqrtf(var + 1e-5f);
#pragma unroll
        for (int ct = 0; ct < 2; ct++) {
            int col = w * 32 + ct * 16 + ln;
            float y = (acc[ct][r] - mu) * rs * lg[col] + lb[col];
            y = y > 0.f ? y : 0.01f * y;
            yv[ct][r] = y;
            t2[r] += y * y;
        }
    }
#pragma unroll
    for (int off = 1; off < 16; off <<= 1)
#pragma unroll
        for (int r = 0; r < 4; r++) t2[r] += __shfl_xor(t2[r], off, 64);
    __syncthreads();
    if (ln == 0)
#pragma unroll
        for (int r = 0; r < 4; r++) pS[w][q * 4 + r] = t2[r];
    __syncthreads();
#pragma unroll
    for (int r = 0; r < 4; r++) {
        int row = q * 4 + r;
        float T = pS[0][row] + pS[1][row] + pS[2][row] + pS[3][row];
        if (w == 0 && ln == 0) rnbuf[row0 + row] = sqrtf(T);
#pragma unroll
        for (int ct = 0; ct < 2; ct++) {
            int col = w * 32 + ct * 16 + ln;
            rout[(size_t)(row0 + row) * 128 + col] = f2bf(yv[ct][r]);
        }
    }
    __syncthreads();
}

__global__ __launch_bounds__(BT, 3) void mega(Args A) {
    __shared__ __align__(16) ushort As[16][136];
    __shared__ __align__(16) ushort z1s[16][264];
    __shared__ float pS[4][16], pQ[4][16];
    __shared__ int scanbuf[BT];
    __shared__ float poolbuf[BT];

    const int b = blockIdx.x, tid = threadIdx.x;
    const int w = tid >> 6, l = tid & 63;
    const int q = l >> 4, ln = l & 15;
    const int GS = GD * BT;
    const int gtid = b * BT + tid;
    int gen = 0;
    uint(*AsU)[68] = (uint(*)[68])As;
    const int N = A.N, E = A.E, L = A.L, Gr = A.G;
    const int TILES = N / 16;

    // ---------------- phase 0: conversions + hist + graph boundaries --------
    for (int idx = gtid; idx < L * 32768; idx += GS) {
        int lz = idx >> 15, il = idx & 32767;
        int col = il >> 7, k = il & 127;
        A.W1t[idx] = f2bf(A.W1[((size_t)lz << 15) + (k << 8) + col]);
    }
    for (int idx = gtid; idx < L * 32768; idx += GS) {
        int lz = idx >> 15, il = idx & 32767;
        int col = il >> 8, k = il & 255;
        A.W2t[idx] = f2bf(A.W2[((size_t)lz << 15) + (k << 7) + col]);
    }
    for (int idx = gtid; idx < 16384; idx += GS) {
        int col = idx >> 7, k = idx & 127;
        A.encWt[idx] = f2bf(A.encW[(k << 7) + col]);
    }
    for (int idx = gtid; idx < N * 128; idx += GS) A.xb[idx] = f2bf(A.x[idx]);
    for (int e = gtid; e < E; e += GS) atomicAdd(&A.deg[A.dst[e]], 1);
    for (int n = gtid; n < N; n += GS) {
        int bb = A.batch[n];
        if (n == 0)
            for (int g = 0; g <= bb; g++) A.gstart[g] = 0;
        else {
            int pb = A.batch[n - 1];
            for (int g = pb + 1; g <= bb; g++) A.gstart[g] = n;
        }
        if (n == N - 1)
            for (int g = bb + 1; g <= Gr; g++) A.gstart[g] = N;
    }
    grid_sync(A.bar, gen);

    // ---------------- phase 1: per-chunk degree sums (chunk = 14 nodes) -----
    {
        int c0 = b * 14;
        if (tid < 64) {
            int idx = c0 + tid;
            int v = (tid < 14 && idx < N) ? A.deg[idx] : 0;
            v = wave_sum_i(v);
            if (tid == 0) A.chunkSum[b] = v;
        }
    }
    grid_sync(A.bar, gen);

    // ---------------- phase 2: block 0 scans 768 chunk sums -----------------
    if (b == 0) {
        int v0 = A.chunkSum[tid * 3], v1 = A.chunkSum[tid * 3 + 1], v2 = A.chunkSum[tid * 3 + 2];
        scanbuf[tid] = v0 + v1 + v2;
        __syncthreads();
        for (int off = 1; off < BT; off <<= 1) {
            int t2 = (tid >= off) ? scanbuf[tid - off] : 0;
            __syncthreads();
            scanbuf[tid] += t2;
            __syncthreads();
        }
        int excl = (tid == 0) ? 0 : scanbuf[tid - 1];
        A.chunkOff[tid * 3] = excl;
        A.chunkOff[tid * 3 + 1] = excl + v0;
        A.chunkOff[tid * 3 + 2] = excl + v0 + v1;
        if (tid == BT - 1) A.chunkOff[GD] = scanbuf[BT - 1];
    }
    grid_sync(A.bar, gen);

    // ---------------- phase 3: offs + cursor per chunk ----------------------
    if (tid == 0) {
        int c0 = b * 14, c1 = min(c0 + 14, N);
        if (c0 < N) {
            int run = A.chunkOff[b];
            for (int ii = c0; ii < c1; ii++) {
                int d = A.deg[ii];
                A.offs[ii] = run;
                A.cursor[ii] = run;
                run += d;
            }
        }
        if (b == 0) A.offs[N] = A.chunkOff[GD];
    }
    grid_sync(A.bar, gen);

    // ---------------- phase 4: scatter edges into CSR -----------------------
    for (int e = gtid; e < E; e += GS) {
        int d = A.dst[e];
        int pos = atomicAdd(&A.cursor[d], 1);
        A.esrc[pos] = A.src[e];
    }
    grid_sync(A.bar, gen);

    // ---------------- phase 5: encoder GEMM + LN0 + lrelu -------------------
    for (int t = b; t < TILES; t += GD) {
        int row0 = t * 16;
        for (int idx = tid; idx < 16 * 64; idx += BT) {
            int row = idx >> 6, cl = idx & 63;
            AsU[row][cl] = ((const uint*)A.xb)[(size_t)(row0 + row) * 64 + cl];
        }
        __syncthreads();
        out_stage<128, false>(&As[0][0], 136, A.encWt, A.encB, A.ln_g, A.ln_b,
                              A.h, A.r0, A.rn, row0, w, q, ln, pS, pQ);
    }
    grid_sync(A.bar, gen);

    // ---------------- layer phases ------------------------------------------
    for (int i = 0; i < L; i++) {
        const ushort* rin = (i & 1) ? A.r1 : A.r0;
        ushort* rout = (i & 1) ? A.r0 : A.r1;
        const float* ng = (i < L - 1) ? (A.ln_g + (size_t)(i + 1) * 128) : A.fn_g;
        const float* nb = (i < L - 1) ? (A.ln_b + (size_t)(i + 1) * 128) : A.fn_b;
        const ushort* W1L = A.W1t + ((size_t)i << 15);
        const ushort* W2L = A.W2t + ((size_t)i << 15);
        const float* b1L = A.b1 + (size_t)i * 256;
        const float* mgL = A.mg + (size_t)i * 256;
        const float* mbL = A.mb + (size_t)i * 256;
        const float* b2L = A.b2 + (size_t)i * 128;
        float tv = A.tArr[i], sv = A.scArr[i];
        for (int t = b; t < TILES; t += GD) {
            int row0 = t * 16;
            agg_stage(rin, A.offs, A.esrc, A.rn, tv, sv, row0, w, l, AsU);
            __syncthreads();
            gemm1_stage(As, W1L, b1L, mgL, mbL, z1s, w, q, ln, pS, pQ);
            out_stage<256, true>(&z1s[0][0], 264, W2L, b2L, ng, nb,
                                 A.h, rout, A.rn, row0, w, q, ln, pS, pQ);
        }
        grid_sync(A.bar, gen);
    }

    // ---------------- pool phase --------------------------------------------
    // last layer i=L-1 wrote rout = ((L-1)&1) ? r0 : r1  ==  (L&1) ? r1 : r0
    if (b < Gr) {
        const ushort* rf = (L & 1) ? A.r1 : A.r0;
        int s = A.gstart[b], e = A.gstart[b + 1];
        int f = tid & 127, half = tid >> 7;
        float acc = 0.f;
        for (int n = s + half; n < e; n += 2) acc += bf2f(rf[(size_t)n * 128 + f]);
        poolbuf[tid] = acc;
        __syncthreads();
        if (tid < 128) {
            float tot = poolbuf[tid] + poolbuf[tid + 128];
            A.out[b * 128 + tid] = tot / fmaxf((float)(e - s), 1.f);
        }
    }
}

// ---------------------------------------------------------------------------
extern "C" void kernel_launch(void* const* d_in, const int* in_sizes, int n_in,
                              void* d_out, int out_size, void* d_ws, size_t ws_size,
                              hipStream_t stream) {
    Args A;
    A.x     = (const float*)d_in[0];
    const int* ei = (const int*)d_in[1];
    A.batch = (const int*)d_in[2];
    A.encW  = (const float*)d_in[3];
    A.encB  = (const float*)d_in[4];
    A.ln_g  = (const float*)d_in[5];
    A.ln_b  = (const float*)d_in[6];
    A.tArr  = (const float*)d_in[7];
    A.scArr = (const float*)d_in[8];
    A.W1    = (const float*)d_in[9];
    A.b1    = (const float*)d_in[10];
    A.mg    = (const float*)d_in[11];
    A.mb    = (const float*)d_in[12];
    A.W2    = (const float*)d_in[13];
    A.b2    = (const float*)d_in[14];
    A.fn_g  = (const float*)d_in[15];
    A.fn_b  = (const float*)d_in[16];
    A.out   = (float*)d_out;

    A.N = in_sizes[0] / 128;
    A.E = in_sizes[1] / 2;
    A.L = in_sizes[7];
    A.G = 64;
    A.src = ei;
    A.dst = ei + A.E;

    char* p = (char*)d_ws;
    auto alloc = [&](size_t bytes) -> void* {
        void* qp = (void*)p;
        p += (bytes + 255) & ~(size_t)255;
        return qp;
    };
    A.bar      = (int*)alloc(256);
    A.deg      = (int*)alloc((size_t)A.N * 4);
    A.offs     = (int*)alloc((size_t)(A.N + 1) * 4);
    A.cursor   = (int*)alloc((size_t)A.N * 4);
    A.esrc     = (int*)alloc((size_t)A.E * 4);
    A.chunkSum = (int*)alloc((size_t)GD * 4);
    A.chunkOff = (int*)alloc((size_t)(GD + 1) * 4);
    A.gstart   = (int*)alloc((size_t)(A.G + 1) * 4);
    A.h        = (float*)alloc((size_t)A.N * 128 * 4);
    A.r0       = (ushort*)alloc((size_t)A.N * 128 * 2);
    A.r1       = (ushort*)alloc((size_t)A.N * 128 * 2);
    A.rn       = (float*)alloc((size_t)A.N * 4);
    A.xb       = (ushort*)alloc((size_t)A.N * 128 * 2);
    A.W1t      = (ushort*)alloc((size_t)A.L * 32768 * 2);
    A.W2t      = (ushort*)alloc((size_t)A.L * 32768 * 2);
    A.encWt    = (ushort*)alloc((size_t)16384 * 2);

    // zero barrier counter + deg histogram (ws is poisoned 0xAA every call)
    hipMemsetAsync(d_ws, 0, 256 + (size_t)A.N * 4, stream);

    mega<<<GD, BT, 0, stream>>>(A);
}

// Round 5
// 844.925 us; speedup vs baseline: 8.0442x; 8.0442x over previous
//
#include <hip/hip_runtime.h>
#include <cstdint>
#include <cstddef>

// ---------------------------------------------------------------------------
// DeeperGCN forward on MI355X. Round 5: per-layer fused kernels (agg + MLP +
// LN epilogues in one dispatch, 625 independent 16-row tiles), NO grid
// barriers (round 4 showed 97% idle waiting on a contended global barrier).
// N=10000 nodes, E=160000 edges, H=128, L=14 layers, G=64 graphs.
// ---------------------------------------------------------------------------

typedef __attribute__((ext_vector_type(8))) short bf16x8;
typedef __attribute__((ext_vector_type(4))) float f32x4;

__device__ inline float bf2f(ushort u) {
    union { uint i; float f; } v;
    v.i = (uint)u << 16;
    return v.f;
}
__device__ inline ushort f2bf(float f) {
    union { float f; uint i; } v;
    v.f = f;
    return (ushort)((v.i + 0x7fffu + ((v.i >> 16) & 1u)) >> 16);
}
__device__ inline uint f2bf2(float a, float b) {
    return (uint)f2bf(a) | ((uint)f2bf(b) << 16);
}

__device__ inline float wave_sum_f(float v) {
#pragma unroll
    for (int off = 32; off > 0; off >>= 1) v += __shfl_xor(v, off, 64);
    return v;
}

// ---------------- setup: xb convert + deg histogram + graph boundaries -----
__global__ void setup_kernel(const float* __restrict__ x, ushort* __restrict__ xb,
                             const int* __restrict__ dst, int* __restrict__ deg,
                             const int* __restrict__ batch, int* __restrict__ gstart,
                             int total, int N, int E, int G) {
    int idx = blockIdx.x * blockDim.x + threadIdx.x;
    if (idx >= total) return;
    xb[idx] = f2bf(x[idx]);
    if (idx < E) atomicAdd(&deg[dst[idx]], 1);
    if (idx < N) {
        int bb = batch[idx];
        if (idx == 0)
            for (int g = 0; g <= bb; g++) gstart[g] = 0;
        else {
            int pb = batch[idx - 1];
            for (int g = pb + 1; g <= bb; g++) gstart[g] = idx;
        }
        if (idx == N - 1)
            for (int g = bb + 1; g <= G; g++) gstart[g] = N;
    }
}

// single-workgroup exclusive scan of deg -> offs, cursor
__global__ __launch_bounds__(1024) void scan_kernel(const int* __restrict__ deg,
                                                    int* __restrict__ offs,
                                                    int* __restrict__ cursor, int N) {
    __shared__ int part[1024];
    int tid = threadIdx.x;
    int CH = (N + 1023) / 1024;
    int base = tid * CH;
    int s = 0;
    for (int i = 0; i < CH; i++) {
        int idx = base + i;
        if (idx < N) s += deg[idx];
    }
    part[tid] = s;
    __syncthreads();
    for (int off = 1; off < 1024; off <<= 1) {
        int v = (tid >= off) ? part[tid - off] : 0;
        __syncthreads();
        part[tid] += v;
        __syncthreads();
    }
    int run = (tid == 0) ? 0 : part[tid - 1];
    for (int i = 0; i < CH; i++) {
        int idx = base + i;
        if (idx < N) {
            offs[idx] = run;
            cursor[idx] = run;
            run += deg[idx];
        }
    }
    if (tid == 1023) offs[N] = part[1023];
}

__global__ void scatter_kernel(const int* __restrict__ src, const int* __restrict__ dst,
                               int* __restrict__ cursor, int* __restrict__ esrc, int E) {
    int e = blockIdx.x * blockDim.x + threadIdx.x;
    if (e < E) {
        int d = dst[e];
        int pos = atomicAdd(&cursor[d], 1);
        esrc[pos] = src[e];
    }
}

// ---------------- weight prep: fp32 [R][C] -> bf16 [C][R], all matrices ----
__global__ __launch_bounds__(256) void prep_kernel(const float* __restrict__ W1,
                                                   const float* __restrict__ W2,
                                                   const float* __restrict__ encW,
                                                   ushort* __restrict__ W1t,
                                                   ushort* __restrict__ W2t,
                                                   ushort* __restrict__ encWt, int L) {
    __shared__ float tile[32][33];
    int z = blockIdx.z;
    const float* in;
    ushort* out;
    int R, C;
    if (z < L) {
        in = W1 + (size_t)z * 32768; out = W1t + (size_t)z * 32768; R = 128; C = 256;
    } else if (z < 2 * L) {
        int i = z - L;
        in = W2 + (size_t)i * 32768; out = W2t + (size_t)i * 32768; R = 256; C = 128;
    } else {
        in = encW; out = encWt; R = 128; C = 128;
    }
    int r0 = blockIdx.y * 32, c0 = blockIdx.x * 32;
    if (r0 >= R || c0 >= C) return;
    int tx = threadIdx.x & 31, ty = threadIdx.x >> 5;
    for (int i = ty; i < 32; i += 8) tile[i][tx] = in[(size_t)(r0 + i) * C + c0 + tx];
    __syncthreads();
    for (int i = ty; i < 32; i += 8)
        out[(size_t)(c0 + i) * R + r0 + tx] = f2bf(tile[tx][i]);
}

// ---- aggregation for 16-node tile; 4 interleaved edge chains per wave -----
__device__ __forceinline__ void agg_stage(const ushort* __restrict__ rin,
                                          const int* __restrict__ offs,
                                          const int* __restrict__ esrc,
                                          const float* __restrict__ rnbuf,
                                          float tv, float sv, int row0,
                                          int w, int l, uint (*AsU)[68]) {
    int base = row0 + w * 4;
    int e0[4], cnt[4];
    int mx = 0;
#pragma unroll
    for (int k = 0; k < 4; k++) {
        e0[k] = offs[base + k];
        cnt[k] = offs[base + k + 1] - e0[k];
        mx = max(mx, cnt[k]);
    }
    float m[4][2], s[4][2], W[4][2];
#pragma unroll
    for (int k = 0; k < 4; k++)
#pragma unroll
        for (int c = 0; c < 2; c++) {
            m[k][c] = -INFINITY; s[k][c] = 0.f; W[k][c] = 0.f;
        }
#pragma unroll 1
    for (int off = 0; off < mx; off++) {
        uint rv[4];
        int val[4];
#pragma unroll
        for (int k = 0; k < 4; k++) {
            val[k] = (off < cnt[k]);
            if (val[k]) {
                int sn = esrc[e0[k] + off];
                rv[k] = ((const uint*)rin)[(size_t)sn * 64 + l];
            }
        }
#pragma unroll
        for (int k = 0; k < 4; k++)
            if (val[k]) {
                float x0 = bf2f((ushort)(rv[k] & 0xffff));
                float x1 = bf2f((ushort)(rv[k] >> 16));
                float g0 = fmaxf(x0, 0.f) + 1e-7f;
                float g1 = fmaxf(x1, 0.f) + 1e-7f;
                float z0 = g0 * tv, z1v = g1 * tv;
                float nm0 = fmaxf(m[k][0], z0), nm1 = fmaxf(m[k][1], z1v);
                float a0 = __expf(m[k][0] - nm0), a1 = __expf(m[k][1] - nm1);
                float p0 = __expf(z0 - nm0), p1 = __expf(z1v - nm1);
                s[k][0] = s[k][0] * a0 + p0;
                s[k][1] = s[k][1] * a1 + p1;
                W[k][0] = W[k][0] * a0 + g0 * p0;
                W[k][1] = W[k][1] * a1 + g1 * p1;
                m[k][0] = nm0;
                m[k][1] = nm1;
            }
    }
#pragma unroll
    for (int k = 0; k < 4; k++) {
        int nd = base + k;
        float agg0 = W[k][0] / (s[k][0] + 1e-16f);
        float agg1 = W[k][1] / (s[k][1] + 1e-16f);
        float nr = sqrtf(wave_sum_f(agg0 * agg0 + agg1 * agg1));
        float fac = rnbuf[nd] * sv / fmaxf(nr, 1e-12f);
        uint ru = ((const uint*)rin)[(size_t)nd * 64 + l];
        float r0v = bf2f((ushort)(ru & 0xffff));
        float r1v = bf2f((ushort)(ru >> 16));
        AsU[w * 4 + k][l] = f2bf2(r0v + agg0 * fac, r1v + agg1 * fac);
    }
}

// ---- gemm1: z1 = relu(LN256(A(16x128) @ W1^T + b1)) into z1s LDS ----------
__device__ __forceinline__ void gemm1_stage(const ushort (*As)[136],
                                            const ushort* __restrict__ Bt,
                                            const float* __restrict__ bias,
                                            const float* __restrict__ mg,
                                            const float* __restrict__ mb,
                                            ushort (*z1s)[264],
                                            int w, int q, int ln,
                                            float (*pS)[16], float (*pQ)[16]) {
    f32x4 acc[4];
#pragma unroll
    for (int ct = 0; ct < 4; ct++) acc[ct] = (f32x4){0.f, 0.f, 0.f, 0.f};
#pragma unroll
    for (int ks = 0; ks < 128; ks += 32) {
        bf16x8 a = *(const bf16x8*)&As[ln][ks + q * 8];
#pragma unroll
        for (int ct = 0; ct < 4; ct++) {
            bf16x8 bv = *(const bf16x8*)(Bt + (size_t)(w * 64 + ct * 16 + ln) * 128 + ks + q * 8);
            acc[ct] = __builtin_amdgcn_mfma_f32_16x16x32_bf16(a, bv, acc[ct], 0, 0, 0);
        }
    }
    float s1[4] = {0, 0, 0, 0}, s2[4] = {0, 0, 0, 0};
#pragma unroll
    for (int ct = 0; ct < 4; ct++)
#pragma unroll
        for (int r = 0; r < 4; r++) {
            float v = acc[ct][r] + bias[w * 64 + ct * 16 + ln];
            acc[ct][r] = v;
            s1[r] += v;
            s2[r] += v * v;
        }
#pragma unroll
    for (int off = 1; off < 16; off <<= 1)
#pragma unroll
        for (int r = 0; r < 4; r++) {
            s1[r] += __shfl_xor(s1[r], off, 64);
            s2[r] += __shfl_xor(s2[r], off, 64);
        }
    if (ln == 0)
#pragma unroll
        for (int r = 0; r < 4; r++) {
            pS[w][q * 4 + r] = s1[r];
            pQ[w][q * 4 + r] = s2[r];
        }
    __syncthreads();
#pragma unroll
    for (int r = 0; r < 4; r++) {
        int row = q * 4 + r;
        float S = pS[0][row] + pS[1][row] + pS[2][row] + pS[3][row];
        float Q = pQ[0][row] + pQ[1][row] + pQ[2][row] + pQ[3][row];
        float mu = S * (1.f / 256.f);
        float var = Q * (1.f / 256.f) - mu * mu;
        float rs = rsqrtf(var + 1e-5f);
#pragma unroll
        for (int ct = 0; ct < 4; ct++) {
            int col = w * 64 + ct * 16 + ln;
            float y = (acc[ct][r] - mu) * rs * mg[col] + mb[col];
            z1s[row][col] = f2bf(fmaxf(y, 0.f));
        }
    }
    __syncthreads();
}

// ---- output gemm: v = A(16xKD) @ B^T + bias (+h); h=v; LN128 -> lrelu ->
// rout (bf16), rn = ||row||. ----
template <int KD, bool RESID>
__device__ __forceinline__ void out_stage(const ushort* __restrict__ Abase, int astr,
                                          const ushort* __restrict__ Bt,
                                          const float* __restrict__ bias,
                                          const float* __restrict__ lg,
                                          const float* __restrict__ lb,
                                          float* __restrict__ hbuf,
                                          ushort* __restrict__ rout,
                                          float* __restrict__ rnbuf,
                                          int row0, int w, int q, int ln,
                                          float (*pS)[16], float (*pQ)[16]) {
    f32x4 acc[2];
    acc[0] = (f32x4){0.f, 0.f, 0.f, 0.f};
    acc[1] = (f32x4){0.f, 0.f, 0.f, 0.f};
#pragma unroll
    for (int ks = 0; ks < KD; ks += 32) {
        bf16x8 a = *(const bf16x8*)(Abase + ln * astr + ks + q * 8);
#pragma unroll
        for (int ct = 0; ct < 2; ct++) {
            bf16x8 bv = *(const bf16x8*)(Bt + (size_t)(w * 32 + ct * 16 + ln) * KD + ks + q * 8);
            acc[ct] = __builtin_amdgcn_mfma_f32_16x16x32_bf16(a, bv, acc[ct], 0, 0, 0);
        }
    }
    float s1[4] = {0, 0, 0, 0}, s2[4] = {0, 0, 0, 0};
#pragma unroll
    for (int ct = 0; ct < 2; ct++)
#pragma unroll
        for (int r = 0; r < 4; r++) {
            int row = q * 4 + r, col = w * 32 + ct * 16 + ln;
            float v = acc[ct][r] + bias[col];
            if (RESID) v += hbuf[(size_t)(row0 + row) * 128 + col];
            hbuf[(size_t)(row0 + row) * 128 + col] = v;
            acc[ct][r] = v;
            s1[r] += v;
            s2[r] += v * v;
        }
#pragma unroll
    for (int off = 1; off < 16; off <<= 1)
#pragma unroll
        for (int r = 0; r < 4; r++) {
            s1[r] += __shfl_xor(s1[r], off, 64);
            s2[r] += __shfl_xor(s2[r], off, 64);
        }
    if (ln == 0)
#pragma unroll
        for (int r = 0; r < 4; r++) {
            pS[w][q * 4 + r] = s1[r];
            pQ[w][q * 4 + r] = s2[r];
        }
    __syncthreads();
    float yv[2][4];
    float t2[4] = {0, 0, 0, 0};
#pragma unroll
    for (int r = 0; r < 4; r++) {
        int row = q * 4 + r;
        float S = pS[0][row] + pS[1][row] + pS[2][row] + pS[3][row];
        float Q = pQ[0][row] + pQ[1][row] + pQ[2][row] + pQ[3][row];
        float mu = S * (1.f / 128.f);
        float var = Q * (1.f / 128.f) - mu * mu;
        float rs = rsqrtf(var + 1e-5f);
#pragma unroll
        for (int ct = 0; ct < 2; ct++) {
            int col = w * 32 + ct * 16 + ln;
            float y = (acc[ct][r] - mu) * rs * lg[col] + lb[col];
            y = y > 0.f ? y : 0.01f * y;
            yv[ct][r] = y;
            t2[r] += y * y;
        }
    }
#pragma unroll
    for (int off = 1; off < 16; off <<= 1)
#pragma unroll
        for (int r = 0; r < 4; r++) t2[r] += __shfl_xor(t2[r], off, 64);
    __syncthreads();
    if (ln == 0)
#pragma unroll
        for (int r = 0; r < 4; r++) pS[w][q * 4 + r] = t2[r];
    __syncthreads();
#pragma unroll
    for (int r = 0; r < 4; r++) {
        int row = q * 4 + r;
        float T = pS[0][row] + pS[1][row] + pS[2][row] + pS[3][row];
        if (w == 0 && ln == 0) rnbuf[row0 + row] = sqrtf(T);
#pragma unroll
        for (int ct = 0; ct < 2; ct++) {
            int col = w * 32 + ct * 16 + ln;
            rout[(size_t)(row0 + row) * 128 + col] = f2bf(yv[ct][r]);
        }
    }
}

// ---------------- encoder: h = xb @ encW^T + b; LN0 + lrelu ----------------
__global__ __launch_bounds__(256) void enc_kernel(const ushort* __restrict__ xb,
                                                  const ushort* __restrict__ encWt,
                                                  const float* __restrict__ encB,
                                                  const float* __restrict__ lg,
                                                  const float* __restrict__ lb,
                                                  float* __restrict__ h,
                                                  ushort* __restrict__ r,
                                                  float* __restrict__ rn, int N) {
    __shared__ __align__(16) ushort As[16][136];
    __shared__ float pS[4][16], pQ[4][16];
    uint(*AsU)[68] = (uint(*)[68])As;
    int tid = threadIdx.x, w = tid >> 6, l = tid & 63;
    int q = l >> 4, ln = l & 15;
    int row0 = blockIdx.x * 16;
    for (int idx = tid; idx < 16 * 64; idx += 256) {
        int row = idx >> 6, cl = idx & 63;
        AsU[row][cl] = ((const uint*)xb)[(size_t)(row0 + row) * 64 + cl];
    }
    __syncthreads();
    out_stage<128, false>(&As[0][0], 136, encWt, encB, lg, lb, h, r, rn,
                          row0, w, q, ln, pS, pQ);
}

// ---------------- fused layer: agg + gemm1(LN,relu) + gemm2(resid,LN,lrelu) -
__global__ __launch_bounds__(256) void layer_kernel(const ushort* __restrict__ rin,
                                                    ushort* __restrict__ rout,
                                                    const int* __restrict__ offs,
                                                    const int* __restrict__ esrc,
                                                    float* __restrict__ rn,
                                                    float* __restrict__ h,
                                                    const ushort* __restrict__ W1t,
                                                    const ushort* __restrict__ W2t,
                                                    const float* __restrict__ b1,
                                                    const float* __restrict__ mg,
                                                    const float* __restrict__ mb,
                                                    const float* __restrict__ b2,
                                                    const float* __restrict__ ng,
                                                    const float* __restrict__ nb,
                                                    const float* __restrict__ tptr,
                                                    const float* __restrict__ scptr,
                                                    int N) {
    __shared__ __align__(16) ushort As[16][136];
    __shared__ __align__(16) ushort z1s[16][264];
    __shared__ float pS[4][16], pQ[4][16];
    uint(*AsU)[68] = (uint(*)[68])As;
    int tid = threadIdx.x, w = tid >> 6, l = tid & 63;
    int q = l >> 4, ln = l & 15;
    int row0 = blockIdx.x * 16;
    float tv = *tptr, sv = *scptr;
    agg_stage(rin, offs, esrc, rn, tv, sv, row0, w, l, AsU);
    __syncthreads();
    gemm1_stage(As, W1t, b1, mg, mb, z1s, w, q, ln, pS, pQ);
    out_stage<256, true>(&z1s[0][0], 264, W2t, b2, ng, nb, h, rout, rn,
                         row0, w, q, ln, pS, pQ);
}

// ---------------- pool: one block per graph, 4 waves over rows -------------
__global__ __launch_bounds__(256) void pool_kernel(const ushort* __restrict__ rf,
                                                   const int* __restrict__ gstart,
                                                   float* __restrict__ out) {
    __shared__ float pb0[4][64], pb1[4][64];
    int g = blockIdx.x;
    int w = threadIdx.x >> 6, l = threadIdx.x & 63;
    int s = gstart[g], e = gstart[g + 1];
    float a0 = 0.f, a1 = 0.f;
    for (int n = s + w; n < e; n += 4) {
        uint rv = ((const uint*)rf)[(size_t)n * 64 + l];
        a0 += bf2f((ushort)(rv & 0xffff));
        a1 += bf2f((ushort)(rv >> 16));
    }
    pb0[w][l] = a0;
    pb1[w][l] = a1;
    __syncthreads();
    if (threadIdx.x < 64) {
        float t0 = pb0[0][l] + pb0[1][l] + pb0[2][l] + pb0[3][l];
        float t1 = pb1[0][l] + pb1[1][l] + pb1[2][l] + pb1[3][l];
        float inv = 1.f / fmaxf((float)(e - s), 1.f);
        out[g * 128 + 2 * l] = t0 * inv;
        out[g * 128 + 2 * l + 1] = t1 * inv;
    }
}

// ---------------------------------------------------------------------------
extern "C" void kernel_launch(void* const* d_in, const int* in_sizes, int n_in,
                              void* d_out, int out_size, void* d_ws, size_t ws_size,
                              hipStream_t stream) {
    const float* x     = (const float*)d_in[0];
    const int*   ei    = (const int*)d_in[1];
    const int*   batch = (const int*)d_in[2];
    const float* encW  = (const float*)d_in[3];
    const float* encB  = (const float*)d_in[4];
    const float* ln_g  = (const float*)d_in[5];
    const float* ln_b  = (const float*)d_in[6];
    const float* tArr  = (const float*)d_in[7];
    const float* scArr = (const float*)d_in[8];
    const float* W1    = (const float*)d_in[9];
    const float* b1    = (const float*)d_in[10];
    const float* mg    = (const float*)d_in[11];
    const float* mb    = (const float*)d_in[12];
    const float* W2    = (const float*)d_in[13];
    const float* b2    = (const float*)d_in[14];
    const float* fn_g  = (const float*)d_in[15];
    const float* fn_b  = (const float*)d_in[16];
    float* out = (float*)d_out;

    const int N = in_sizes[0] / 128;  // 10000
    const int E = in_sizes[1] / 2;    // 160000
    const int L = in_sizes[7];        // 14
    const int G = 64;

    const int* src = ei;
    const int* dst = ei + E;

    char* p = (char*)d_ws;
    auto alloc = [&](size_t bytes) -> void* {
        void* qp = (void*)p;
        p += (bytes + 255) & ~(size_t)255;
        return qp;
    };
    int*    deg    = (int*)alloc((size_t)N * 4);
    int*    offs   = (int*)alloc((size_t)(N + 1) * 4);
    int*    cursor = (int*)alloc((size_t)N * 4);
    int*    esrc   = (int*)alloc((size_t)E * 4);
    int*    gstart = (int*)alloc((size_t)(G + 1) * 4);
    float*  h      = (float*)alloc((size_t)N * 128 * 4);
    ushort* r0     = (ushort*)alloc((size_t)N * 128 * 2);
    ushort* r1     = (ushort*)alloc((size_t)N * 128 * 2);
    float*  rn     = (float*)alloc((size_t)N * 4);
    ushort* xb     = (ushort*)alloc((size_t)N * 128 * 2);
    ushort* W1t    = (ushort*)alloc((size_t)L * 32768 * 2);
    ushort* W2t    = (ushort*)alloc((size_t)L * 32768 * 2);
    ushort* encWt  = (ushort*)alloc((size_t)16384 * 2);

    hipMemsetAsync(deg, 0, (size_t)N * 4, stream);

    setup_kernel<<<(N * 128 + 255) / 256, 256, 0, stream>>>(x, xb, dst, deg, batch,
                                                            gstart, N * 128, N, E, G);
    scan_kernel<<<1, 1024, 0, stream>>>(deg, offs, cursor, N);
    scatter_kernel<<<(E + 255) / 256, 256, 0, stream>>>(src, dst, cursor, esrc, E);
    prep_kernel<<<dim3(8, 8, 2 * L + 1), 256, 0, stream>>>(W1, W2, encW, W1t, W2t,
                                                           encWt, L);

    const int TILES = N / 16;  // 625

    enc_kernel<<<TILES, 256, 0, stream>>>(xb, encWt, encB, ln_g, ln_b, h, r0, rn, N);

    for (int i = 0; i < L; i++) {
        const ushort* rin = (i & 1) ? r1 : r0;
        ushort* rout = (i & 1) ? r0 : r1;
        const float* ng = (i < L - 1) ? (ln_g + (size_t)(i + 1) * 128) : fn_g;
        const float* nb = (i < L - 1) ? (ln_b + (size_t)(i + 1) * 128) : fn_b;
        layer_kernel<<<TILES, 256, 0, stream>>>(rin, rout, offs, esrc, rn, h,
                                                W1t + ((size_t)i << 15),
                                                W2t + ((size_t)i << 15),
                                                b1 + (size_t)i * 256,
                                                mg + (size_t)i * 256,
                                                mb + (size_t)i * 256,
                                                b2 + (size_t)i * 128,
                                                ng, nb, tArr + i, scArr + i, N);
    }

    // last layer i=L-1 wrote rout = ((L-1)&1) ? r0 : r1
    const ushort* rf = ((L - 1) & 1) ? r0 : r1;
    pool_kernel<<<G, 256, 0, stream>>>(rf, gstart, out);
}

// Round 6
// 719.779 us; speedup vs baseline: 9.4428x; 1.1739x over previous
//
#include <hip/hip_runtime.h>
#include <cstdint>
#include <cstddef>

// ---------------------------------------------------------------------------
// DeeperGCN forward on MI355X. Round 6: per-layer fused kernels at 512
// threads/block (8 waves): agg does 2 nodes x 2 interleaved edge chains per
// wave (half the serial iterations, 2x the resident waves vs round 5's
// latency-bound 4-wave version).
// N=10000 nodes, E=160000 edges, H=128, L=14 layers, G=64 graphs.
// ---------------------------------------------------------------------------

#define BT 512  // 8 waves

typedef __attribute__((ext_vector_type(8))) short bf16x8;
typedef __attribute__((ext_vector_type(4))) float f32x4;

__device__ inline float bf2f(ushort u) {
    union { uint i; float f; } v;
    v.i = (uint)u << 16;
    return v.f;
}
__device__ inline ushort f2bf(float f) {
    union { float f; uint i; } v;
    v.f = f;
    return (ushort)((v.i + 0x7fffu + ((v.i >> 16) & 1u)) >> 16);
}
__device__ inline uint f2bf2(float a, float b) {
    return (uint)f2bf(a) | ((uint)f2bf(b) << 16);
}

__device__ inline float wave_sum_f(float v) {
#pragma unroll
    for (int off = 32; off > 0; off >>= 1) v += __shfl_xor(v, off, 64);
    return v;
}

// ---------------- setup: xb convert + deg histogram + graph boundaries -----
__global__ void setup_kernel(const float* __restrict__ x, ushort* __restrict__ xb,
                             const int* __restrict__ dst, int* __restrict__ deg,
                             const int* __restrict__ batch, int* __restrict__ gstart,
                             int total, int N, int E, int G) {
    int idx = blockIdx.x * blockDim.x + threadIdx.x;
    if (idx >= total) return;
    xb[idx] = f2bf(x[idx]);
    if (idx < E) atomicAdd(&deg[dst[idx]], 1);
    if (idx < N) {
        int bb = batch[idx];
        if (idx == 0)
            for (int g = 0; g <= bb; g++) gstart[g] = 0;
        else {
            int pb = batch[idx - 1];
            for (int g = pb + 1; g <= bb; g++) gstart[g] = idx;
        }
        if (idx == N - 1)
            for (int g = bb + 1; g <= G; g++) gstart[g] = N;
    }
}

// single-workgroup exclusive scan of deg -> offs, cursor
__global__ __launch_bounds__(1024) void scan_kernel(const int* __restrict__ deg,
                                                    int* __restrict__ offs,
                                                    int* __restrict__ cursor, int N) {
    __shared__ int part[1024];
    int tid = threadIdx.x;
    int CH = (N + 1023) / 1024;
    int base = tid * CH;
    int s = 0;
    for (int i = 0; i < CH; i++) {
        int idx = base + i;
        if (idx < N) s += deg[idx];
    }
    part[tid] = s;
    __syncthreads();
    for (int off = 1; off < 1024; off <<= 1) {
        int v = (tid >= off) ? part[tid - off] : 0;
        __syncthreads();
        part[tid] += v;
        __syncthreads();
    }
    int run = (tid == 0) ? 0 : part[tid - 1];
    for (int i = 0; i < CH; i++) {
        int idx = base + i;
        if (idx < N) {
            offs[idx] = run;
            cursor[idx] = run;
            run += deg[idx];
        }
    }
    if (tid == 1023) offs[N] = part[1023];
}

__global__ void scatter_kernel(const int* __restrict__ src, const int* __restrict__ dst,
                               int* __restrict__ cursor, int* __restrict__ esrc, int E) {
    int e = blockIdx.x * blockDim.x + threadIdx.x;
    if (e < E) {
        int d = dst[e];
        int pos = atomicAdd(&cursor[d], 1);
        esrc[pos] = src[e];
    }
}

// ---------------- weight prep: fp32 [R][C] -> bf16 [C][R], all matrices ----
__global__ __launch_bounds__(256) void prep_kernel(const float* __restrict__ W1,
                                                   const float* __restrict__ W2,
                                                   const float* __restrict__ encW,
                                                   ushort* __restrict__ W1t,
                                                   ushort* __restrict__ W2t,
                                                   ushort* __restrict__ encWt, int L) {
    __shared__ float tile[32][33];
    int z = blockIdx.z;
    const float* in;
    ushort* out;
    int R, C;
    if (z < L) {
        in = W1 + (size_t)z * 32768; out = W1t + (size_t)z * 32768; R = 128; C = 256;
    } else if (z < 2 * L) {
        int i = z - L;
        in = W2 + (size_t)i * 32768; out = W2t + (size_t)i * 32768; R = 256; C = 128;
    } else {
        in = encW; out = encWt; R = 128; C = 128;
    }
    int r0 = blockIdx.y * 32, c0 = blockIdx.x * 32;
    if (r0 >= R || c0 >= C) return;
    int tx = threadIdx.x & 31, ty = threadIdx.x >> 5;
    for (int i = ty; i < 32; i += 8) tile[i][tx] = in[(size_t)(r0 + i) * C + c0 + tx];
    __syncthreads();
    for (int i = ty; i < 32; i += 8)
        out[(size_t)(c0 + i) * R + r0 + tx] = f2bf(tile[tx][i]);
}

// ---- aggregation: wave w handles nodes row0+2w{,+1}, 2 edge chains each ----
__device__ __forceinline__ void agg_stage8(const ushort* __restrict__ rin,
                                           const int* __restrict__ offs,
                                           const int* __restrict__ esrc,
                                           const float* __restrict__ rnbuf,
                                           float tv, float sv, int row0,
                                           int w, int l, uint (*AsU)[68]) {
    int base = row0 + w * 2;
    int e00 = offs[base], e01 = offs[base + 1], e02 = offs[base + 2];
    int eb[2] = {e00, e01};
    int cn[2] = {e01 - e00, e02 - e01};
    float m[2][2][2], s[2][2][2], W[2][2][2];
#pragma unroll
    for (int k = 0; k < 2; k++)
#pragma unroll
        for (int c = 0; c < 2; c++)
#pragma unroll
            for (int f = 0; f < 2; f++) {
                m[k][c][f] = -INFINITY;
                s[k][c][f] = 0.f;
                W[k][c][f] = 0.f;
            }
    int mx = max((cn[0] + 1) >> 1, (cn[1] + 1) >> 1);
#pragma unroll 1
    for (int off = 0; off < mx; off++) {
        uint rv[2][2];
        bool val[2][2];
#pragma unroll
        for (int k = 0; k < 2; k++)
#pragma unroll
            for (int c = 0; c < 2; c++) {
                int j = 2 * off + c;
                val[k][c] = j < cn[k];
                if (val[k][c]) {
                    int sn = esrc[eb[k] + j];
                    rv[k][c] = ((const uint*)rin)[(size_t)sn * 64 + l];
                }
            }
#pragma unroll
        for (int k = 0; k < 2; k++)
#pragma unroll
            for (int c = 0; c < 2; c++)
                if (val[k][c]) {
                    float x0 = bf2f((ushort)(rv[k][c] & 0xffff));
                    float x1 = bf2f((ushort)(rv[k][c] >> 16));
                    float g0 = fmaxf(x0, 0.f) + 1e-7f;
                    float g1 = fmaxf(x1, 0.f) + 1e-7f;
                    float z0 = g0 * tv, z1v = g1 * tv;
                    float nm0 = fmaxf(m[k][c][0], z0), nm1 = fmaxf(m[k][c][1], z1v);
                    float a0 = __expf(m[k][c][0] - nm0), a1 = __expf(m[k][c][1] - nm1);
                    float p0 = __expf(z0 - nm0), p1 = __expf(z1v - nm1);
                    s[k][c][0] = s[k][c][0] * a0 + p0;
                    s[k][c][1] = s[k][c][1] * a1 + p1;
                    W[k][c][0] = W[k][c][0] * a0 + g0 * p0;
                    W[k][c][1] = W[k][c][1] * a1 + g1 * p1;
                    m[k][c][0] = nm0;
                    m[k][c][1] = nm1;
                }
    }
#pragma unroll
    for (int k = 0; k < 2; k++) {
        float agg[2];
#pragma unroll
        for (int f = 0; f < 2; f++) {
            // merge the two online-softmax chains (guard double -inf -> 0)
            float mm = fmaxf(m[k][0][f], m[k][1][f]);
            float eA = (m[k][0][f] > -INFINITY) ? __expf(m[k][0][f] - mm) : 0.f;
            float eB = (m[k][1][f] > -INFINITY) ? __expf(m[k][1][f] - mm) : 0.f;
            float ss = s[k][0][f] * eA + s[k][1][f] * eB;
            float WW = W[k][0][f] * eA + W[k][1][f] * eB;
            agg[f] = WW / (ss + 1e-16f);
        }
        int nd = base + k;
        float nr = sqrtf(wave_sum_f(agg[0] * agg[0] + agg[1] * agg[1]));
        float fac = rnbuf[nd] * sv / fmaxf(nr, 1e-12f);
        uint ru = ((const uint*)rin)[(size_t)nd * 64 + l];
        AsU[w * 2 + k][l] = f2bf2(bf2f((ushort)(ru & 0xffff)) + agg[0] * fac,
                                  bf2f((ushort)(ru >> 16)) + agg[1] * fac);
    }
}

// ---- gemm1 (8 waves): z1 = relu(LN256(A(16x128) @ W1^T + b1)) into LDS ----
__device__ __forceinline__ void gemm1_stage8(const ushort (*As)[136],
                                             const ushort* __restrict__ Bt,
                                             const float* __restrict__ bias,
                                             const float* __restrict__ mg,
                                             const float* __restrict__ mb,
                                             ushort (*z1s)[264],
                                             int w, int q, int ln,
                                             float (*pS)[16], float (*pQ)[16]) {
    f32x4 acc[2];
    acc[0] = (f32x4){0.f, 0.f, 0.f, 0.f};
    acc[1] = (f32x4){0.f, 0.f, 0.f, 0.f};
#pragma unroll
    for (int ks = 0; ks < 128; ks += 32) {
        bf16x8 a = *(const bf16x8*)&As[ln][ks + q * 8];
#pragma unroll
        for (int ct = 0; ct < 2; ct++) {
            bf16x8 bv = *(const bf16x8*)(Bt + (size_t)(w * 32 + ct * 16 + ln) * 128 + ks + q * 8);
            acc[ct] = __builtin_amdgcn_mfma_f32_16x16x32_bf16(a, bv, acc[ct], 0, 0, 0);
        }
    }
    float s1[4] = {0, 0, 0, 0}, s2[4] = {0, 0, 0, 0};
#pragma unroll
    for (int ct = 0; ct < 2; ct++)
#pragma unroll
        for (int r = 0; r < 4; r++) {
            float v = acc[ct][r] + bias[w * 32 + ct * 16 + ln];
            acc[ct][r] = v;
            s1[r] += v;
            s2[r] += v * v;
        }
#pragma unroll
    for (int off = 1; off < 16; off <<= 1)
#pragma unroll
        for (int r = 0; r < 4; r++) {
            s1[r] += __shfl_xor(s1[r], off, 64);
            s2[r] += __shfl_xor(s2[r], off, 64);
        }
    if (ln == 0)
#pragma unroll
        for (int r = 0; r < 4; r++) {
            pS[w][q * 4 + r] = s1[r];
            pQ[w][q * 4 + r] = s2[r];
        }
    __syncthreads();
#pragma unroll
    for (int r = 0; r < 4; r++) {
        int row = q * 4 + r;
        float S = 0.f, Q = 0.f;
#pragma unroll
        for (int ww = 0; ww < 8; ww++) {
            S += pS[ww][row];
            Q += pQ[ww][row];
        }
        float mu = S * (1.f / 256.f);
        float var = Q * (1.f / 256.f) - mu * mu;
        float rs = rsqrtf(var + 1e-5f);
#pragma unroll
        for (int ct = 0; ct < 2; ct++) {
            int col = w * 32 + ct * 16 + ln;
            float y = (acc[ct][r] - mu) * rs * mg[col] + mb[col];
            z1s[row][col] = f2bf(fmaxf(y, 0.f));
        }
    }
    __syncthreads();
}

// ---- out gemm (8 waves): v = A(16xKD)@B^T + bias (+h); h=v; LN128+lrelu ----
template <int KD, bool RESID>
__device__ __forceinline__ void out_stage8(const ushort* __restrict__ Abase, int astr,
                                           const ushort* __restrict__ Bt,
                                           const float* __restrict__ bias,
                                           const float* __restrict__ lg,
                                           const float* __restrict__ lb,
                                           float* __restrict__ hbuf,
                                           ushort* __restrict__ rout,
                                           float* __restrict__ rnbuf,
                                           int row0, int w, int q, int ln,
                                           float (*pS)[16], float (*pQ)[16]) {
    f32x4 acc = (f32x4){0.f, 0.f, 0.f, 0.f};
    int col = w * 16 + ln;
#pragma unroll
    for (int ks = 0; ks < KD; ks += 32) {
        bf16x8 a = *(const bf16x8*)(Abase + ln * astr + ks + q * 8);
        bf16x8 bv = *(const bf16x8*)(Bt + (size_t)col * KD + ks + q * 8);
        acc = __builtin_amdgcn_mfma_f32_16x16x32_bf16(a, bv, acc, 0, 0, 0);
    }
    float s1[4], s2[4];
#pragma unroll
    for (int r = 0; r < 4; r++) {
        int row = q * 4 + r;
        float v = acc[r] + bias[col];
        if (RESID) v += hbuf[(size_t)(row0 + row) * 128 + col];
        hbuf[(size_t)(row0 + row) * 128 + col] = v;
        acc[r] = v;
        s1[r] = v;
        s2[r] = v * v;
    }
#pragma unroll
    for (int off = 1; off < 16; off <<= 1)
#pragma unroll
        for (int r = 0; r < 4; r++) {
            s1[r] += __shfl_xor(s1[r], off, 64);
            s2[r] += __shfl_xor(s2[r], off, 64);
        }
    if (ln == 0)
#pragma unroll
        for (int r = 0; r < 4; r++) {
            pS[w][q * 4 + r] = s1[r];
            pQ[w][q * 4 + r] = s2[r];
        }
    __syncthreads();
    float yv[4];
    float t2[4];
#pragma unroll
    for (int r = 0; r < 4; r++) {
        int row = q * 4 + r;
        float S = 0.f, Q = 0.f;
#pragma unroll
        for (int ww = 0; ww < 8; ww++) {
            S += pS[ww][row];
            Q += pQ[ww][row];
        }
        float mu = S * (1.f / 128.f);
        float var = Q * (1.f / 128.f) - mu * mu;
        float rs = rsqrtf(var + 1e-5f);
        float y = (acc[r] - mu) * rs * lg[col] + lb[col];
        y = y > 0.f ? y : 0.01f * y;
        yv[r] = y;
        t2[r] = y * y;
    }
#pragma unroll
    for (int off = 1; off < 16; off <<= 1)
#pragma unroll
        for (int r = 0; r < 4; r++) t2[r] += __shfl_xor(t2[r], off, 64);
    __syncthreads();
    if (ln == 0)
#pragma unroll
        for (int r = 0; r < 4; r++) pS[w][q * 4 + r] = t2[r];
    __syncthreads();
#pragma unroll
    for (int r = 0; r < 4; r++) {
        int row = q * 4 + r;
        float T = 0.f;
#pragma unroll
        for (int ww = 0; ww < 8; ww++) T += pS[ww][row];
        if (w == 0 && ln == 0) rnbuf[row0 + row] = sqrtf(T);
        rout[(size_t)(row0 + row) * 128 + col] = f2bf(yv[r]);
    }
}

// ---------------- encoder: h = xb @ encW^T + b; LN0 + lrelu ----------------
__global__ __launch_bounds__(BT) void enc_kernel(const ushort* __restrict__ xb,
                                                 const ushort* __restrict__ encWt,
                                                 const float* __restrict__ encB,
                                                 const float* __restrict__ lg,
                                                 const float* __restrict__ lb,
                                                 float* __restrict__ h,
                                                 ushort* __restrict__ r,
                                                 float* __restrict__ rn, int N) {
    __shared__ __align__(16) ushort As[16][136];
    __shared__ float pS[8][16], pQ[8][16];
    uint(*AsU)[68] = (uint(*)[68])As;
    int tid = threadIdx.x, w = tid >> 6, l = tid & 63;
    int q = l >> 4, ln = l & 15;
    int row0 = blockIdx.x * 16;
    for (int idx = tid; idx < 16 * 64; idx += BT) {
        int row = idx >> 6, cl = idx & 63;
        AsU[row][cl] = ((const uint*)xb)[(size_t)(row0 + row) * 64 + cl];
    }
    __syncthreads();
    out_stage8<128, false>(&As[0][0], 136, encWt, encB, lg, lb, h, r, rn,
                           row0, w, q, ln, pS, pQ);
}

// ---------------- fused layer: agg + gemm1(LN,relu) + gemm2(resid,LN,lrelu) -
__global__ __launch_bounds__(BT) void layer_kernel(const ushort* __restrict__ rin,
                                                   ushort* __restrict__ rout,
                                                   const int* __restrict__ offs,
                                                   const int* __restrict__ esrc,
                                                   float* __restrict__ rn,
                                                   float* __restrict__ h,
                                                   const ushort* __restrict__ W1t,
                                                   const ushort* __restrict__ W2t,
                                                   const float* __restrict__ b1,
                                                   const float* __restrict__ mg,
                                                   const float* __restrict__ mb,
                                                   const float* __restrict__ b2,
                                                   const float* __restrict__ ng,
                                                   const float* __restrict__ nb,
                                                   const float* __restrict__ tptr,
                                                   const float* __restrict__ scptr,
                                                   int N) {
    __shared__ __align__(16) ushort As[16][136];
    __shared__ __align__(16) ushort z1s[16][264];
    __shared__ float pS[8][16], pQ[8][16];
    uint(*AsU)[68] = (uint(*)[68])As;
    int tid = threadIdx.x, w = tid >> 6, l = tid & 63;
    int q = l >> 4, ln = l & 15;
    int row0 = blockIdx.x * 16;
    float tv = *tptr, sv = *scptr;
    agg_stage8(rin, offs, esrc, rn, tv, sv, row0, w, l, AsU);
    __syncthreads();
    gemm1_stage8(As, W1t, b1, mg, mb, z1s, w, q, ln, pS, pQ);
    out_stage8<256, true>(&z1s[0][0], 264, W2t, b2, ng, nb, h, rout, rn,
                          row0, w, q, ln, pS, pQ);
}

// ---------------- pool: one block per graph, 4 waves over rows -------------
__global__ __launch_bounds__(256) void pool_kernel(const ushort* __restrict__ rf,
                                                   const int* __restrict__ gstart,
                                                   float* __restrict__ out) {
    __shared__ float pb0[4][64], pb1[4][64];
    int g = blockIdx.x;
    int w = threadIdx.x >> 6, l = threadIdx.x & 63;
    int s = gstart[g], e = gstart[g + 1];
    float a0 = 0.f, a1 = 0.f;
    for (int n = s + w; n < e; n += 4) {
        uint rv = ((const uint*)rf)[(size_t)n * 64 + l];
        a0 += bf2f((ushort)(rv & 0xffff));
        a1 += bf2f((ushort)(rv >> 16));
    }
    pb0[w][l] = a0;
    pb1[w][l] = a1;
    __syncthreads();
    if (threadIdx.x < 64) {
        float t0 = pb0[0][l] + pb0[1][l] + pb0[2][l] + pb0[3][l];
        float t1 = pb1[0][l] + pb1[1][l] + pb1[2][l] + pb1[3][l];
        float inv = 1.f / fmaxf((float)(e - s), 1.f);
        out[g * 128 + 2 * l] = t0 * inv;
        out[g * 128 + 2 * l + 1] = t1 * inv;
    }
}

// ---------------------------------------------------------------------------
extern "C" void kernel_launch(void* const* d_in, const int* in_sizes, int n_in,
                              void* d_out, int out_size, void* d_ws, size_t ws_size,
                              hipStream_t stream) {
    const float* x     = (const float*)d_in[0];
    const int*   ei    = (const int*)d_in[1];
    const int*   batch = (const int*)d_in[2];
    const float* encW  = (const float*)d_in[3];
    const float* encB  = (const float*)d_in[4];
    const float* ln_g  = (const float*)d_in[5];
    const float* ln_b  = (const float*)d_in[6];
    const float* tArr  = (const float*)d_in[7];
    const float* scArr = (const float*)d_in[8];
    const float* W1    = (const float*)d_in[9];
    const float* b1    = (const float*)d_in[10];
    const float* mg    = (const float*)d_in[11];
    const float* mb    = (const float*)d_in[12];
    const float* W2    = (const float*)d_in[13];
    const float* b2    = (const float*)d_in[14];
    const float* fn_g  = (const float*)d_in[15];
    const float* fn_b  = (const float*)d_in[16];
    float* out = (float*)d_out;

    const int N = in_sizes[0] / 128;  // 10000
    const int E = in_sizes[1] / 2;    // 160000
    const int L = in_sizes[7];        // 14
    const int G = 64;

    const int* src = ei;
    const int* dst = ei + E;

    char* p = (char*)d_ws;
    auto alloc = [&](size_t bytes) -> void* {
        void* qp = (void*)p;
        p += (bytes + 255) & ~(size_t)255;
        return qp;
    };
    int*    deg    = (int*)alloc((size_t)N * 4);
    int*    offs   = (int*)alloc((size_t)(N + 1) * 4);
    int*    cursor = (int*)alloc((size_t)N * 4);
    int*    esrc   = (int*)alloc((size_t)E * 4);
    int*    gstart = (int*)alloc((size_t)(G + 1) * 4);
    float*  h      = (float*)alloc((size_t)N * 128 * 4);
    ushort* r0     = (ushort*)alloc((size_t)N * 128 * 2);
    ushort* r1     = (ushort*)alloc((size_t)N * 128 * 2);
    float*  rn     = (float*)alloc((size_t)N * 4);
    ushort* xb     = (ushort*)alloc((size_t)N * 128 * 2);
    ushort* W1t    = (ushort*)alloc((size_t)L * 32768 * 2);
    ushort* W2t    = (ushort*)alloc((size_t)L * 32768 * 2);
    ushort* encWt  = (ushort*)alloc((size_t)16384 * 2);

    hipMemsetAsync(deg, 0, (size_t)N * 4, stream);

    setup_kernel<<<(N * 128 + 255) / 256, 256, 0, stream>>>(x, xb, dst, deg, batch,
                                                            gstart, N * 128, N, E, G);
    scan_kernel<<<1, 1024, 0, stream>>>(deg, offs, cursor, N);
    scatter_kernel<<<(E + 255) / 256, 256, 0, stream>>>(src, dst, cursor, esrc, E);
    prep_kernel<<<dim3(8, 8, 2 * L + 1), 256, 0, stream>>>(W1, W2, encW, W1t, W2t,
                                                           encWt, L);

    const int TILES = N / 16;  // 625

    enc_kernel<<<TILES, BT, 0, stream>>>(xb, encWt, encB, ln_g, ln_b, h, r0, rn, N);

    for (int i = 0; i < L; i++) {
        const ushort* rin = (i & 1) ? r1 : r0;
        ushort* rout = (i & 1) ? r0 : r1;
        const float* ng = (i < L - 1) ? (ln_g + (size_t)(i + 1) * 128) : fn_g;
        const float* nb = (i < L - 1) ? (ln_b + (size_t)(i + 1) * 128) : fn_b;
        layer_kernel<<<TILES, BT, 0, stream>>>(rin, rout, offs, esrc, rn, h,
                                               W1t + ((size_t)i << 15),
                                               W2t + ((size_t)i << 15),
                                               b1 + (size_t)i * 256,
                                               mg + (size_t)i * 256,
                                               mb + (size_t)i * 256,
                                               b2 + (size_t)i * 128,
                                               ng, nb, tArr + i, scArr + i, N);
    }

    // last layer i=L-1 wrote rout = ((L-1)&1) ? r0 : r1
    const ushort* rf = ((L - 1) & 1) ? r0 : r1;
    pool_kernel<<<G, 256, 0, stream>>>(rf, gstart, out);
}